// Round 1
// baseline (571.294 us; speedup 1.0000x reference)
//
#include <hip/hip_runtime.h>
#include <cstdint>

// Problem constants: B=64, C=256, H=W=28
#define NB 64
#define NC 256
#define HW 784              // 28*28
#define NPIX (NB*HW)        // 50176 pixels
#define NELEM (NB*NC*HW)    // 12,845,056
#define WORDS 8             // 256 channels / 32 bits

// ---------------------------------------------------------------------------
// Pack weights: one block per (conv, cout). Computes alpha = mean|w|,
// packed sign bits wp[cout][tap(9)][word(8)], and border-correction table
// corr[cout][16] = sum of per-tap positive-bit counts over invalid taps.
// ---------------------------------------------------------------------------
__global__ __launch_bounds__(256) void pack_weights(
    const float* __restrict__ w1, const float* __restrict__ w2,
    uint32_t* __restrict__ wp1, uint32_t* __restrict__ wp2,
    uint16_t* __restrict__ corr1, uint16_t* __restrict__ corr2,
    float* __restrict__ alpha1, float* __restrict__ alpha2) {
  int blk = blockIdx.x;
  int conv = blk >> 8, cout = blk & 255;
  const float* w = (conv ? w2 : w1) + (size_t)cout * 2304;
  uint32_t* wp = (conv ? wp2 : wp1) + cout * 72;
  uint16_t* corr = (conv ? corr2 : corr1) + cout * 16;
  float* alpha = conv ? alpha2 : alpha1;

  int t = threadIdx.x;            // t = cin (0..255)
  float wv9[9];
  float asum = 0.0f;
#pragma unroll
  for (int k = 0; k < 9; ++k) { wv9[k] = w[t * 9 + k]; asum += fabsf(wv9[k]); }

  __shared__ float red[256];
  red[t] = asum;
  __syncthreads();
  for (int s = 128; s > 0; s >>= 1) {
    if (t < s) red[t] += red[t + s];
    __syncthreads();
  }
  if (t == 0) alpha[cout] = red[0] / 2304.0f;

  __shared__ int popw[9];
  if (t < 9) popw[t] = 0;
  __syncthreads();

  int wvid = t >> 6, lane = t & 63;
#pragma unroll
  for (int k = 0; k < 9; ++k) {
    unsigned long long m = __ballot(wv9[k] > 0.0f);
    if (lane == 0) {
      wp[k * 8 + 2 * wvid]     = (uint32_t)m;
      wp[k * 8 + 2 * wvid + 1] = (uint32_t)(m >> 32);
      atomicAdd(&popw[k], __popcll(m));
    }
  }
  __syncthreads();

  if (t < 16) {
    int top = t & 1, bot = (t >> 1) & 1, left = (t >> 2) & 1, right = (t >> 3) & 1;
    int s = 0;
    for (int ky = 0; ky < 3; ++ky)
      for (int kx = 0; kx < 3; ++kx) {
        bool inval = (top && ky == 0) || (bot && ky == 2) ||
                     (left && kx == 0) || (right && kx == 2);
        if (inval) s += popw[ky * 3 + kx];
      }
    corr[t] = (uint16_t)s;
  }
}

// ---------------------------------------------------------------------------
// Pack activations: sign bits of float tensor [64,256,28,28] (NCHW) into
// packed[pixel][word], pixel = (b*28+h)*28+w, word = c/32, bit = c%32.
// One block per (b,h); lane = channel.
// ---------------------------------------------------------------------------
__global__ __launch_bounds__(256) void pack_acts(
    const float* __restrict__ in, uint32_t* __restrict__ out) {
  int blk = blockIdx.x;           // b*28 + h
  int b = blk / 28, h = blk % 28;
  int c = threadIdx.x;
  int wv = c >> 6, lane = c & 63;
  const float* row = in + (((size_t)(b * NC + c)) * 28 + h) * 28;
  for (int w = 0; w < 28; ++w) {
    float v = row[w];
    unsigned long long m = __ballot(v > 0.0f);
    if (lane == 0) {
      int pix = blk * 28 + w;
      out[pix * 8 + 2 * wv]     = (uint32_t)m;
      out[pix * 8 + 2 * wv + 1] = (uint32_t)(m >> 32);
    }
  }
}

// ---------------------------------------------------------------------------
// XNOR conv 3x3 pad 1. Grid = 196 pixel-blocks x 8 cout-groups (of 32).
// Thread = one pixel; inner loop over 32 couts with weights in LDS.
// dot = 256*nvalid - 2*popcount(a^w) + 2*corr ;  y = dot * 0.1*alpha[cout]
// ---------------------------------------------------------------------------
__global__ __launch_bounds__(256) void conv_xnor(
    const uint32_t* __restrict__ ap, const uint32_t* __restrict__ wp,
    const uint16_t* __restrict__ corr, const float* __restrict__ alpha,
    float* __restrict__ y) {
  int pixblk = blockIdx.x % 196;
  int cg = blockIdx.x / 196;
  int cbase = cg * 32;

  __shared__ uint32_t swp[32 * 72];
  __shared__ uint16_t scorr[32 * 16];
  __shared__ float salpha[32];

  int t = threadIdx.x;
  for (int i = t; i < 32 * 72; i += 256) swp[i] = wp[cbase * 72 + i];
  for (int i = t; i < 32 * 16; i += 256) scorr[i] = corr[cbase * 16 + i];
  if (t < 32) salpha[t] = alpha[cbase + t] * 0.1f;

  int p = pixblk * 256 + t;       // 0..50175
  int b = p / HW, hw = p % HW;
  int h = hw / 28, w = hw % 28;

  uint32_t a[9][8];
  int nv = 0;
#pragma unroll
  for (int ky = 0; ky < 3; ++ky) {
#pragma unroll
    for (int kx = 0; kx < 3; ++kx) {
      int hh = h + ky - 1, ww = w + kx - 1;
      int k = ky * 3 + kx;
      if (hh >= 0 && hh < 28 && ww >= 0 && ww < 28) {
        const uint4* s4 =
            reinterpret_cast<const uint4*>(ap + ((size_t)b * HW + hh * 28 + ww) * 8);
        uint4 lo = s4[0], hi = s4[1];
        a[k][0] = lo.x; a[k][1] = lo.y; a[k][2] = lo.z; a[k][3] = lo.w;
        a[k][4] = hi.x; a[k][5] = hi.y; a[k][6] = hi.z; a[k][7] = hi.w;
        nv++;
      } else {
#pragma unroll
        for (int wd = 0; wd < 8; ++wd) a[k][wd] = 0u;
      }
    }
  }
  int cse = (h == 0 ? 1 : 0) | (h == 27 ? 2 : 0) | (w == 0 ? 4 : 0) | (w == 27 ? 8 : 0);
  int base_b = 256 * nv;
  __syncthreads();

  float* yrow = y + (size_t)b * NC * HW + hw;
  for (int co = 0; co < 32; ++co) {
    const uint32_t* wrow = &swp[co * 72];
    int T = 0;
#pragma unroll
    for (int k = 0; k < 9; ++k) {
#pragma unroll
      for (int wd = 0; wd < 8; ++wd) T += __popc(a[k][wd] ^ wrow[k * 8 + wd]);
    }
    int dot = base_b - 2 * T + 2 * (int)scorr[co * 16 + cse];
    yrow[(size_t)(cbase + co) * HW] = (float)dot * salpha[co];
  }
}

// ---------------------------------------------------------------------------
// BN stats: one block per channel; deterministic tree reduction.
// var = E[x^2] - E[x]^2  (biased, matches jnp.var)
// ---------------------------------------------------------------------------
__global__ __launch_bounds__(256) void bn_stats(
    const float* __restrict__ y, float* __restrict__ mean, float* __restrict__ rsv) {
  int c = blockIdx.x, t = threadIdx.x;
  float s = 0.0f, s2 = 0.0f;
  const float* p = y + (size_t)c * HW;
  for (int b = 0; b < NB; ++b) {
    const float* pb = p + (size_t)b * NC * HW;
    for (int i = t; i < HW; i += 256) { float v = pb[i]; s += v; s2 += v * v; }
  }
  __shared__ float rs[256], rs2[256];
  rs[t] = s; rs2[t] = s2;
  __syncthreads();
  for (int st = 128; st > 0; st >>= 1) {
    if (t < st) { rs[t] += rs[t + st]; rs2[t] += rs2[t + st]; }
    __syncthreads();
  }
  if (t == 0) {
    float m = rs[0] / (float)(NB * HW);
    float var = rs2[0] / (float)(NB * HW) - m * m;
    mean[c] = m;
    rsv[c] = rsqrtf(var + 1e-5f);
  }
}

// ---------------------------------------------------------------------------
// BN apply + residual + PReLU (elementwise).  out may alias y (in-place).
// ---------------------------------------------------------------------------
__global__ __launch_bounds__(256) void bn_apply(
    const float* __restrict__ y, const float* __restrict__ res,
    const float* __restrict__ mean, const float* __restrict__ rsv,
    const float* __restrict__ gamma, const float* __restrict__ beta,
    const float* __restrict__ pa, float* __restrict__ out) {
  size_t i = (size_t)blockIdx.x * 256 + threadIdx.x;
  int c = (int)((i / HW) & (NC - 1));
  float a = pa[0];
  float v = (y[i] - mean[c]) * rsv[c] * gamma[c] + beta[c] + res[i];
  out[i] = v >= 0.0f ? v : a * v;
}

// ---------------------------------------------------------------------------
extern "C" void kernel_launch(void* const* d_in, const int* in_sizes, int n_in,
                              void* d_out, int out_size, void* d_ws, size_t ws_size,
                              hipStream_t stream) {
  const float* x   = (const float*)d_in[0];
  const float* w1  = (const float*)d_in[1];
  const float* w2  = (const float*)d_in[2];
  const float* g1  = (const float*)d_in[3];
  const float* b1  = (const float*)d_in[4];
  const float* g2  = (const float*)d_in[5];
  const float* b2  = (const float*)d_in[6];
  const float* pa1 = (const float*)d_in[7];
  const float* pa2 = (const float*)d_in[8];
  float* out = (float*)d_out;

  char* ws = (char*)d_ws;
  float*    a1     = (float*)ws;    ws += (size_t)NELEM * 4;        // 51.4 MB
  uint32_t* a0p    = (uint32_t*)ws; ws += (size_t)NPIX * 8 * 4;     // 1.6 MB
  uint32_t* a1p    = (uint32_t*)ws; ws += (size_t)NPIX * 8 * 4;     // 1.6 MB
  uint32_t* wp1    = (uint32_t*)ws; ws += 256 * 72 * 4;
  uint32_t* wp2    = (uint32_t*)ws; ws += 256 * 72 * 4;
  uint16_t* corr1  = (uint16_t*)ws; ws += 256 * 16 * 2;
  uint16_t* corr2  = (uint16_t*)ws; ws += 256 * 16 * 2;
  float*    alpha1 = (float*)ws;    ws += 1024;
  float*    alpha2 = (float*)ws;    ws += 1024;
  float*    mean1  = (float*)ws;    ws += 1024;
  float*    rsv1   = (float*)ws;    ws += 1024;
  float*    mean2  = (float*)ws;    ws += 1024;
  float*    rsv2   = (float*)ws;    ws += 1024;

  // Stage 0: pack weights & input signs
  pack_weights<<<512, 256, 0, stream>>>(w1, w2, wp1, wp2, corr1, corr2, alpha1, alpha2);
  pack_acts<<<NB * 28, 256, 0, stream>>>(x, a0p);

  // Stage 1: conv1 -> d_out(y1); BN1 stats; apply+residual+PReLU -> a1
  conv_xnor<<<196 * 8, 256, 0, stream>>>(a0p, wp1, corr1, alpha1, out);
  bn_stats<<<256, 256, 0, stream>>>(out, mean1, rsv1);
  bn_apply<<<NELEM / 256, 256, 0, stream>>>(out, x, mean1, rsv1, g1, b1, pa1, a1);

  // Stage 2: conv2 -> d_out(y2); BN2 stats; apply+residual+PReLU in-place
  pack_acts<<<NB * 28, 256, 0, stream>>>(a1, a1p);
  conv_xnor<<<196 * 8, 256, 0, stream>>>(a1p, wp2, corr2, alpha2, out);
  bn_stats<<<256, 256, 0, stream>>>(out, mean2, rsv2);
  bn_apply<<<NELEM / 256, 256, 0, stream>>>(out, a1, mean2, rsv2, g2, b2, pa2, out);
}

// Round 2
// 269.130 us; speedup vs baseline: 2.1227x; 2.1227x over previous
//
#include <hip/hip_runtime.h>
#include <cstdint>

#define NB 64
#define NC 256
#define HW 784              // 28*28
#define NPIX (NB*HW)        // 50176
#define NELEM ((size_t)NB*NC*HW)

// ---------------------------------------------------------------------------
// Zero the integer stat accumulators (1024 u64).
// ---------------------------------------------------------------------------
__global__ __launch_bounds__(256) void init_stats(unsigned long long* s) {
  int i = blockIdx.x * 256 + threadIdx.x;
  if (i < 1024) s[i] = 0ull;
}

// ---------------------------------------------------------------------------
// Pack weights: one block per (conv, cout). alpha = mean|w|, packed sign bits
// wp[cout][tap(9)][word(8)], corr[cout][16] border-correction table.
// ---------------------------------------------------------------------------
__global__ __launch_bounds__(256) void pack_weights(
    const float* __restrict__ w1, const float* __restrict__ w2,
    uint32_t* __restrict__ wp1, uint32_t* __restrict__ wp2,
    uint16_t* __restrict__ corr1, uint16_t* __restrict__ corr2,
    float* __restrict__ alpha1, float* __restrict__ alpha2) {
  int blk = blockIdx.x;
  int conv = blk >> 8, cout = blk & 255;
  const float* w = (conv ? w2 : w1) + (size_t)cout * 2304;
  uint32_t* wp = (conv ? wp2 : wp1) + cout * 72;
  uint16_t* corr = (conv ? corr2 : corr1) + cout * 16;
  float* alpha = conv ? alpha2 : alpha1;

  int t = threadIdx.x;            // t = cin (0..255)
  float wv9[9];
  float asum = 0.0f;
#pragma unroll
  for (int k = 0; k < 9; ++k) { wv9[k] = w[t * 9 + k]; asum += fabsf(wv9[k]); }

  __shared__ float red[256];
  red[t] = asum;
  __syncthreads();
  for (int s = 128; s > 0; s >>= 1) {
    if (t < s) red[t] += red[t + s];
    __syncthreads();
  }
  if (t == 0) alpha[cout] = red[0] / 2304.0f;

  __shared__ int popw[9];
  if (t < 9) popw[t] = 0;
  __syncthreads();

  int wvid = t >> 6, lane = t & 63;
#pragma unroll
  for (int k = 0; k < 9; ++k) {
    unsigned long long m = __ballot(wv9[k] > 0.0f);
    if (lane == 0) {
      wp[k * 8 + 2 * wvid]     = (uint32_t)m;
      wp[k * 8 + 2 * wvid + 1] = (uint32_t)(m >> 32);
      atomicAdd(&popw[k], __popcll(m));
    }
  }
  __syncthreads();

  if (t < 16) {
    int top = t & 1, bot = (t >> 1) & 1, left = (t >> 2) & 1, right = (t >> 3) & 1;
    int s = 0;
    for (int ky = 0; ky < 3; ++ky)
      for (int kx = 0; kx < 3; ++kx) {
        bool inval = (top && ky == 0) || (bot && ky == 2) ||
                     (left && kx == 0) || (right && kx == 2);
        if (inval) s += popw[ky * 3 + kx];
      }
    corr[t] = (uint16_t)s;
  }
}

// ---------------------------------------------------------------------------
// Coalesced sign-pack via LDS transpose. Block = 32 global pixels x 256 c.
// ---------------------------------------------------------------------------
__global__ __launch_bounds__(256) void pack_transpose(
    const float* __restrict__ in, uint32_t* __restrict__ outp) {
  __shared__ float tile[256 * 33];
  int t = threadIdx.x;
  int P0 = blockIdx.x * 32;
#pragma unroll
  for (int i = 0; i < 32; ++i) {
    int j = i * 256 + t;
    int c = j >> 5, pl = j & 31;
    int P = P0 + pl;
    int b = P / HW, hw = P - b * HW;
    tile[c * 33 + pl] = in[(size_t)b * (NC * HW) + (size_t)c * HW + hw];
  }
  __syncthreads();
  int w = t >> 6, l = t & 63;
  int c = w * 64 + l;
  for (int pl = 0; pl < 32; ++pl) {
    float v = tile[c * 33 + pl];
    unsigned long long m = __ballot(v > 0.0f);
    if (l == 0) {
      int P = P0 + pl;
      outp[P * 8 + 2 * w]     = (uint32_t)m;
      outp[P * 8 + 2 * w + 1] = (uint32_t)(m >> 32);
    }
  }
}

// ---------------------------------------------------------------------------
// XNOR conv 3x3 pad 1 + fused exact integer BN-stat partials.
// Weights read via wave-uniform global loads (SGPR path, no LDS stream).
// ---------------------------------------------------------------------------
__global__ __launch_bounds__(256) void conv_xnor(
    const uint32_t* __restrict__ ap, const uint32_t* __restrict__ wp,
    const uint16_t* __restrict__ corr, const float* __restrict__ alpha,
    float* __restrict__ y, unsigned long long* __restrict__ sdot,
    unsigned long long* __restrict__ sdot2) {
  int pixblk = blockIdx.x % 196;
  int cg = blockIdx.x / 196;
  int cbase = cg * 32;

  __shared__ uint16_t scorr[32 * 16];
  __shared__ float salpha[32];
  __shared__ int sD[32 * 4], sD2[32 * 4];

  int t = threadIdx.x;
  for (int i = t; i < 32 * 16; i += 256) scorr[i] = corr[cbase * 16 + i];
  if (t < 32) salpha[t] = alpha[cbase + t] * 0.1f;

  int p = pixblk * 256 + t;       // 0..50175
  int b = p / HW, hw = p - b * HW;
  int h = hw / 28, w = hw - h * 28;

  uint32_t a[9][8];
  int nv = 0;
#pragma unroll
  for (int ky = 0; ky < 3; ++ky) {
#pragma unroll
    for (int kx = 0; kx < 3; ++kx) {
      int hh = h + ky - 1, ww = w + kx - 1;
      int k = ky * 3 + kx;
      if (hh >= 0 && hh < 28 && ww >= 0 && ww < 28) {
        const uint4* s4 =
            reinterpret_cast<const uint4*>(ap + ((size_t)b * HW + hh * 28 + ww) * 8);
        uint4 lo = s4[0], hi = s4[1];
        a[k][0] = lo.x; a[k][1] = lo.y; a[k][2] = lo.z; a[k][3] = lo.w;
        a[k][4] = hi.x; a[k][5] = hi.y; a[k][6] = hi.z; a[k][7] = hi.w;
        nv++;
      } else {
#pragma unroll
        for (int wd = 0; wd < 8; ++wd) a[k][wd] = 0u;
      }
    }
  }
  int cse = (h == 0 ? 1 : 0) | (h == 27 ? 2 : 0) | (w == 0 ? 4 : 0) | (w == 27 ? 8 : 0);
  int base_b = 256 * nv;
  int lane = t & 63, wid = t >> 6;
  __syncthreads();

  float* yrow = y + (size_t)b * (NC * HW) + hw;
  const uint32_t* wbase = wp + cbase * 72;   // wave-uniform
  for (int co = 0; co < 32; ++co) {
    const uint32_t* wr = wbase + co * 72;    // uniform -> s_load
    int T = 0;
#pragma unroll
    for (int k = 0; k < 9; ++k) {
#pragma unroll
      for (int wd = 0; wd < 8; ++wd) T += __popc(a[k][wd] ^ wr[k * 8 + wd]);
    }
    int dot = base_b - 2 * T + 2 * (int)scorr[co * 16 + cse];
    yrow[(size_t)(cbase + co) * HW] = (float)dot * salpha[co];

    int d = dot, d2 = dot * dot;             // d2 <= 5.3e6, wave-sum < 2^31
#pragma unroll
    for (int off = 1; off < 64; off <<= 1) {
      d  += __shfl_xor(d, off);
      d2 += __shfl_xor(d2, off);
    }
    if (lane == 0) { sD[co * 4 + wid] = d; sD2[co * 4 + wid] = d2; }
  }
  __syncthreads();
  if (t < 32) {
    long long D = 0, D2 = 0;
    for (int wv = 0; wv < 4; ++wv) { D += sD[t * 4 + wv]; D2 += sD2[t * 4 + wv]; }
    atomicAdd(&sdot [cbase + t], (unsigned long long)D);
    atomicAdd(&sdot2[cbase + t], (unsigned long long)D2);
  }
}

// ---------------------------------------------------------------------------
// Finalize BN: scale[c] = rsv*gamma, shift[c] = beta - mean*rsv*gamma.
// mean/var from exact integer sums of dot and dot^2 (y = dot * 0.1*alpha).
// ---------------------------------------------------------------------------
__global__ __launch_bounds__(256) void bn_finalize(
    const unsigned long long* __restrict__ sdot,
    const unsigned long long* __restrict__ sdot2,
    const float* __restrict__ alpha, const float* __restrict__ gamma,
    const float* __restrict__ beta, float* __restrict__ scale,
    float* __restrict__ shift) {
  int c = threadIdx.x;
  long long D = (long long)sdot[c], D2 = (long long)sdot2[c];
  float sc = 0.1f * alpha[c];
  const float invN = 1.0f / (float)(NB * HW);
  float m   = sc * ((float)D * invN);
  float ex2 = sc * sc * ((float)D2 * invN);
  float var = ex2 - m * m;
  float rs = rsqrtf(var + 1e-5f);
  float g = gamma[c];
  scale[c] = rs * g;
  shift[c] = beta[c] - m * rs * g;
}

// ---------------------------------------------------------------------------
// BN apply + residual + PReLU + sign-pack (LDS transpose), coalesced.
// ---------------------------------------------------------------------------
__global__ __launch_bounds__(256) void bn_apply_pack(
    const float* __restrict__ y, const float* __restrict__ res,
    const float* __restrict__ scale, const float* __restrict__ shift,
    const float* __restrict__ pa,
    float* __restrict__ outa, uint32_t* __restrict__ outp) {
  __shared__ float tile[256 * 33];
  __shared__ float ssc[256], ssh[256];
  int t = threadIdx.x;
  ssc[t] = scale[t]; ssh[t] = shift[t];
  float ap = pa[0];
  __syncthreads();
  int P0 = blockIdx.x * 32;
#pragma unroll
  for (int i = 0; i < 32; ++i) {
    int j = i * 256 + t;
    int c = j >> 5, pl = j & 31;
    int P = P0 + pl;
    int b = P / HW, hw = P - b * HW;
    size_t addr = (size_t)b * (NC * HW) + (size_t)c * HW + hw;
    float v = fmaf(y[addr], ssc[c], ssh[c]) + res[addr];
    float o = v >= 0.0f ? v : ap * v;
    outa[addr] = o;
    tile[c * 33 + pl] = v;
  }
  __syncthreads();
  int w = t >> 6, l = t & 63;
  int c = w * 64 + l;
  for (int pl = 0; pl < 32; ++pl) {
    float v = tile[c * 33 + pl];
    unsigned long long m = __ballot(v > 0.0f);
    if (l == 0) {
      int P = P0 + pl;
      outp[P * 8 + 2 * w]     = (uint32_t)m;
      outp[P * 8 + 2 * w + 1] = (uint32_t)(m >> 32);
    }
  }
}

// ---------------------------------------------------------------------------
// Final BN apply + residual + PReLU, vectorized float4, in-place on d_out.
// ---------------------------------------------------------------------------
__global__ __launch_bounds__(256) void bn_apply_final(
    const float4* __restrict__ y, const float4* __restrict__ res,
    const float* __restrict__ scale, const float* __restrict__ shift,
    const float* __restrict__ pa, float4* __restrict__ out) {
  int i4 = blockIdx.x * 256 + threadIdx.x;   // NELEM/4
  int c = (i4 / 196) & 255;                  // 196 float4 per (b,c) row
  float sc = scale[c], sh = shift[c], ap = pa[0];
  float4 v = y[i4], r = res[i4];
  float4 o;
  o.x = fmaf(v.x, sc, sh) + r.x; o.x = o.x >= 0.0f ? o.x : ap * o.x;
  o.y = fmaf(v.y, sc, sh) + r.y; o.y = o.y >= 0.0f ? o.y : ap * o.y;
  o.z = fmaf(v.z, sc, sh) + r.z; o.z = o.z >= 0.0f ? o.z : ap * o.z;
  o.w = fmaf(v.w, sc, sh) + r.w; o.w = o.w >= 0.0f ? o.w : ap * o.w;
  out[i4] = o;
}

// ---------------------------------------------------------------------------
extern "C" void kernel_launch(void* const* d_in, const int* in_sizes, int n_in,
                              void* d_out, int out_size, void* d_ws, size_t ws_size,
                              hipStream_t stream) {
  const float* x   = (const float*)d_in[0];
  const float* w1  = (const float*)d_in[1];
  const float* w2  = (const float*)d_in[2];
  const float* g1  = (const float*)d_in[3];
  const float* b1  = (const float*)d_in[4];
  const float* g2  = (const float*)d_in[5];
  const float* b2  = (const float*)d_in[6];
  const float* pa1 = (const float*)d_in[7];
  const float* pa2 = (const float*)d_in[8];
  float* out = (float*)d_out;

  char* ws = (char*)d_ws;
  float*    a1     = (float*)ws;    ws += NELEM * 4;                 // 51.4 MB
  uint32_t* a0p    = (uint32_t*)ws; ws += (size_t)NPIX * 8 * 4;      // 1.6 MB
  uint32_t* a1p    = (uint32_t*)ws; ws += (size_t)NPIX * 8 * 4;      // 1.6 MB
  uint32_t* wp1    = (uint32_t*)ws; ws += 256 * 72 * 4;
  uint32_t* wp2    = (uint32_t*)ws; ws += 256 * 72 * 4;
  uint16_t* corr1  = (uint16_t*)ws; ws += 256 * 16 * 2;
  uint16_t* corr2  = (uint16_t*)ws; ws += 256 * 16 * 2;
  float*    alpha1 = (float*)ws;    ws += 1024;
  float*    alpha2 = (float*)ws;    ws += 1024;
  unsigned long long* stats = (unsigned long long*)ws; ws += 1024 * 8; // 8 KB
  float*    scale1 = (float*)ws;    ws += 1024;
  float*    shift1 = (float*)ws;    ws += 1024;
  float*    scale2 = (float*)ws;    ws += 1024;
  float*    shift2 = (float*)ws;    ws += 1024;

  unsigned long long* sd1 = stats;
  unsigned long long* sq1 = stats + 256;
  unsigned long long* sd2 = stats + 512;
  unsigned long long* sq2 = stats + 768;

  init_stats<<<4, 256, 0, stream>>>(stats);
  pack_weights<<<512, 256, 0, stream>>>(w1, w2, wp1, wp2, corr1, corr2, alpha1, alpha2);
  pack_transpose<<<NPIX / 32, 256, 0, stream>>>(x, a0p);

  conv_xnor<<<196 * 8, 256, 0, stream>>>(a0p, wp1, corr1, alpha1, out, sd1, sq1);
  bn_finalize<<<1, 256, 0, stream>>>(sd1, sq1, alpha1, g1, b1, scale1, shift1);
  bn_apply_pack<<<NPIX / 32, 256, 0, stream>>>(out, x, scale1, shift1, pa1, a1, a1p);

  conv_xnor<<<196 * 8, 256, 0, stream>>>(a1p, wp2, corr2, alpha2, out, sd2, sq2);
  bn_finalize<<<1, 256, 0, stream>>>(sd2, sq2, alpha2, g2, b2, scale2, shift2);
  bn_apply_final<<<(int)(NELEM / 4 / 256), 256, 0, stream>>>(
      (const float4*)out, (const float4*)a1, scale2, shift2, pa2, (float4*)out);
}

// Round 3
// 211.260 us; speedup vs baseline: 2.7042x; 1.2739x over previous
//
#include <hip/hip_runtime.h>
#include <cstdint>

#define NB 64
#define NC 256
#define HW 784              // 28*28
#define NPIX (NB*HW)        // 50176
#define NELEM ((size_t)NB*NC*HW)

typedef int v4i  __attribute__((ext_vector_type(4)));
typedef int v16i __attribute__((ext_vector_type(16)));

union U16 { signed char b[16]; int4 v; };

// ---------------------------------------------------------------------------
__global__ __launch_bounds__(256) void init_stats(unsigned long long* s) {
  int i = blockIdx.x * 256 + threadIdx.x;
  if (i < 1024) s[i] = 0ull;
}

// ---------------------------------------------------------------------------
// alpha = mean|w| per (conv, cout). One block per (conv,cout), coalesced.
// ---------------------------------------------------------------------------
__global__ __launch_bounds__(256) void alpha_k(
    const float* __restrict__ w1, const float* __restrict__ w2,
    float* __restrict__ al1, float* __restrict__ al2) {
  int blk = blockIdx.x;
  int conv = blk >> 8, cout = blk & 255;
  const float* w = (conv ? w2 : w1) + (size_t)cout * 2304;
  int t = threadIdx.x;
  float s = 0.0f;
  for (int i = t; i < 2304; i += 256) s += fabsf(w[i]);
  __shared__ float red[256];
  red[t] = s;
  __syncthreads();
  for (int st = 128; st > 0; st >>= 1) {
    if (t < st) red[t] += red[t + st];
    __syncthreads();
  }
  if (t == 0) (conv ? al2 : al1)[cout] = red[0] / 2304.0f;
}

// ---------------------------------------------------------------------------
// Pack weights into MFMA B-fragment order: Wf[tap][chunk(8)][cgroup(8)][lane(64)][16]
// value = sign(w[cout = cg*32+(lane&31)][cin = chunk*32+(lane>>5)*16+bb][tap])
// ---------------------------------------------------------------------------
__global__ __launch_bounds__(256) void wfrag_k(
    const float* __restrict__ w1, const float* __restrict__ w2,
    signed char* __restrict__ Wf1, signed char* __restrict__ Wf2) {
  int bi = blockIdx.x;            // 144 = 2 conv x 9 tap x 8 cgroup
  int conv = bi / 72, r = bi % 72, tap = r >> 3, cg = r & 7;
  const float* w = conv ? w2 : w1;
  signed char* Wf = conv ? Wf2 : Wf1;
  int t = threadIdx.x;
  for (int e = t; e < 512; e += 256) {
    int c = e >> 6, lane = e & 63;
    int cout = cg * 32 + (lane & 31);
    int cin0 = c * 32 + (lane >> 5) * 16;
    U16 u;
#pragma unroll
    for (int bb = 0; bb < 16; ++bb) {
      float v = w[((size_t)cout * 256 + cin0 + bb) * 9 + tap];
      u.b[bb] = v > 0.f ? 1 : (v < 0.f ? -1 : 0);
    }
    *(int4*)(Wf + ((((size_t)tap * 8 + c) * 8 + cg) * 64 + lane) * 16) = u.v;
  }
}

// ---------------------------------------------------------------------------
// x (NCHW f32) -> int8 signs, pixel-major [p][256]. LDS transpose, coalesced.
// ---------------------------------------------------------------------------
__global__ __launch_bounds__(256) void pack_x(
    const float* __restrict__ in, signed char* __restrict__ A) {
  __shared__ float tile[256 * 33];
  int t = threadIdx.x;
  int P0 = blockIdx.x * 32;
  int pl = t & 31, c0 = t >> 5;
  int P = P0 + pl;
  int b = P / HW, hw = P - b * HW;
  size_t base = (size_t)b * (NC * HW) + (size_t)c0 * HW + hw;
#pragma unroll
  for (int i = 0; i < 32; ++i)
    tile[(i * 8 + c0) * 33 + pl] = in[base + (size_t)i * 8 * HW];
  __syncthreads();
  int g = t >> 4, pls = t & 15;
#pragma unroll
  for (int ph = 0; ph < 2; ++ph) {
    int pp = ph * 16 + pls;
    U16 u;
#pragma unroll
    for (int bb = 0; bb < 16; ++bb) {
      float v = tile[(g * 16 + bb) * 33 + pp];
      u.b[bb] = v > 0.f ? 1 : (v < 0.f ? -1 : 0);
    }
    *(int4*)(A + (size_t)(P0 + pp) * 256 + g * 16) = u.v;
  }
}

// ---------------------------------------------------------------------------
// int8 MFMA conv 3x3 pad 1 + fused exact integer BN stats.
// Block: 128 pixels x 128 couts; 4 waves of 64x64; halo staged once (48KB).
// ---------------------------------------------------------------------------
__global__ __launch_bounds__(256) void conv_mfma(
    const signed char* __restrict__ A, const signed char* __restrict__ Wf,
    short* __restrict__ dotb,
    unsigned long long* __restrict__ sdot,
    unsigned long long* __restrict__ sdot2) {
  __shared__ signed char As[192 * 256];
  int t = threadIdx.x;
  int lane = t & 63, wid = t >> 6;
  int mblk = blockIdx.x >> 1, nblk = blockIdx.x & 1;
  int p0 = mblk * 128;
  int wm = wid & 1, wn = wid >> 1;
  int khalf = lane >> 5;

  // stage halo rows p0-29 .. p0+162 with granule swizzle (key = pixel&15)
  {
    const signed char* src = A + (size_t)(p0 - 29) * 256;
#pragma unroll
    for (int i = 0; i < 12; ++i) {
      int off = i * 4096 + t * 16;
      int4 d = *(const int4*)(src + off);
      int r = off >> 8, g = (off >> 4) & 15;
      int gs = g ^ ((r + 3) & 15);      // (p0-29+r)&15 with p0%16==0
      *(int4*)(As + r * 256 + gs * 16) = d;
    }
  }

  // per-lane pixel geometry for the 2 M-fragments
  int prow[2], hh[2], ww[2];
#pragma unroll
  for (int i = 0; i < 2; ++i) {
    int p = p0 + wm * 64 + i * 32 + (lane & 31);
    prow[i] = p;
    int hw = p % HW;
    hh[i] = hw / 28;
    ww[i] = hw - hh[i] * 28;
  }
  __syncthreads();

  v16i acc00 = {0}, acc01 = {0}, acc10 = {0}, acc11 = {0};
  int cgbase = nblk * 4 + wn * 2;
  const v4i z4 = {0, 0, 0, 0};

  for (int ky = 0; ky < 3; ++ky) {
    for (int kx = 0; kx < 3; ++kx) {
      int tap = ky * 3 + kx;
      int dlt = (ky - 1) * 28 + (kx - 1);
      int rb[2], key[2];
      bool val[2];
#pragma unroll
      for (int i = 0; i < 2; ++i) {
        int hp = hh[i] + ky - 1, wp = ww[i] + kx - 1;
        val[i] = ((unsigned)hp < 28u) && ((unsigned)wp < 28u);
        int pr = prow[i] + dlt;
        rb[i] = (pr - (p0 - 29)) * 256;
        key[i] = pr & 15;
      }
      const signed char* wt = Wf + (size_t)tap * 65536;
#pragma unroll
      for (int c = 0; c < 8; ++c) {
        int gl = c * 2 + khalf;
        v4i a0 = *(const v4i*)(As + rb[0] + ((gl ^ key[0]) << 4));
        v4i a1 = *(const v4i*)(As + rb[1] + ((gl ^ key[1]) << 4));
        a0 = val[0] ? a0 : z4;
        a1 = val[1] ? a1 : z4;
        v4i w0 = *(const v4i*)(wt + (((size_t)c * 8 + cgbase) * 64 + lane) * 16);
        v4i w1 = *(const v4i*)(wt + (((size_t)c * 8 + cgbase + 1) * 64 + lane) * 16);
        acc00 = __builtin_amdgcn_mfma_i32_32x32x32_i8(a0, w0, acc00, 0, 0, 0);
        acc01 = __builtin_amdgcn_mfma_i32_32x32x32_i8(a0, w1, acc01, 0, 0, 0);
        acc10 = __builtin_amdgcn_mfma_i32_32x32x32_i8(a1, w0, acc10, 0, 0, 0);
        acc11 = __builtin_amdgcn_mfma_i32_32x32x32_i8(a1, w1, acc11, 0, 0, 0);
      }
    }
  }

  // stats: per-cout sums of dot and dot^2 over this wave's 64 rows
  int cb = nblk * 128 + wn * 64;
  int s0 = 0, sq0 = 0, s1 = 0, sq1 = 0;
#pragma unroll
  for (int q = 0; q < 16; ++q) {
    s0 += acc00[q] + acc10[q];
    sq0 += acc00[q] * acc00[q] + acc10[q] * acc10[q];
    s1 += acc01[q] + acc11[q];
    sq1 += acc01[q] * acc01[q] + acc11[q] * acc11[q];
  }
  s0 += __shfl_xor(s0, 32); sq0 += __shfl_xor(sq0, 32);
  s1 += __shfl_xor(s1, 32); sq1 += __shfl_xor(sq1, 32);
  if (lane < 32) {
    atomicAdd(&sdot [cb + lane],      (unsigned long long)(long long)s0);
    atomicAdd(&sdot2[cb + lane],      (unsigned long long)(long long)sq0);
    atomicAdd(&sdot [cb + 32 + lane], (unsigned long long)(long long)s1);
    atomicAdd(&sdot2[cb + 32 + lane], (unsigned long long)(long long)sq1);
  }

  // store dot int16, pixel-major [p][256]
#pragma unroll
  for (int i = 0; i < 2; ++i) {
    v16i aj0 = i ? acc10 : acc00;
    v16i aj1 = i ? acc11 : acc01;
    int pr = p0 + wm * 64 + i * 32 + 4 * khalf;
#pragma unroll
    for (int q = 0; q < 16; ++q) {
      int row = pr + (q & 3) + 8 * (q >> 2);
      size_t base = (size_t)row * 256 + cb + (lane & 31);
      dotb[base]      = (short)aj0[q];
      dotb[base + 32] = (short)aj1[q];
    }
  }
}

// ---------------------------------------------------------------------------
// Finalize BN from exact integer sums. y = dot*0.1*alpha.
// scale[c] applies to raw dot; shift[c] absolute.
// ---------------------------------------------------------------------------
__global__ __launch_bounds__(256) void bn_finalize(
    const unsigned long long* __restrict__ sdot,
    const unsigned long long* __restrict__ sdot2,
    const float* __restrict__ alpha, const float* __restrict__ gamma,
    const float* __restrict__ beta, float* __restrict__ scale,
    float* __restrict__ shift) {
  int c = threadIdx.x;
  long long D = (long long)sdot[c], D2 = (long long)sdot2[c];
  float sc = 0.1f * alpha[c];
  const float invN = 1.0f / (float)(NB * HW);
  float md  = (float)D * invN;               // mean of dot
  float ex2 = (float)D2 * invN;
  float var = sc * sc * (ex2 - md * md);
  float rs = rsqrtf(var + 1e-5f);
  float g = gamma[c];
  scale[c] = rs * g * sc;
  shift[c] = beta[c] - sc * md * rs * g;
}

// ---------------------------------------------------------------------------
// BN apply + residual + PReLU + int8 sign-pack.  dot int16 pixel-major in,
// x NCHW in, a1 NCHW out (aliases d_out is fine elsewhere), A int8 out.
// ---------------------------------------------------------------------------
__global__ __launch_bounds__(256) void bn_mid(
    const short* __restrict__ dot, const float* __restrict__ x,
    const float* __restrict__ scale, const float* __restrict__ shift,
    const float* __restrict__ pa, float* __restrict__ a1,
    signed char* __restrict__ A) {
  __shared__ short rawd[32 * 264];
  __shared__ float tile[256 * 33];
  __shared__ float ssc[256], ssh[256];
  int t = threadIdx.x;
  int P0 = blockIdx.x * 32;
  ssc[t] = scale[t]; ssh[t] = shift[t];
  float ap = pa[0];
#pragma unroll
  for (int i = 0; i < 4; ++i) {
    int idx = i * 256 + t;
    int pl = idx >> 5, g = idx & 31;
    int4 d = *(const int4*)(dot + (size_t)(P0 + pl) * 256 + g * 8);
    *(int4*)(&rawd[pl * 264 + g * 8]) = d;
  }
  __syncthreads();
  int pl = t & 31, c0 = t >> 5;
  int P = P0 + pl;
  int b = P / HW, hw = P - b * HW;
  size_t base = (size_t)b * (NC * HW) + (size_t)c0 * HW + hw;
#pragma unroll
  for (int i = 0; i < 32; ++i) {
    int c = i * 8 + c0;
    size_t addr = base + (size_t)i * 8 * HW;
    float d = (float)rawd[pl * 264 + c];
    float v = fmaf(d, ssc[c], ssh[c]) + x[addr];
    float o = v >= 0.0f ? v : ap * v;
    a1[addr] = o;
    tile[c * 33 + pl] = o;
  }
  __syncthreads();
  int g = t >> 4, pls = t & 15;
#pragma unroll
  for (int ph = 0; ph < 2; ++ph) {
    int pp = ph * 16 + pls;
    U16 u;
#pragma unroll
    for (int bb = 0; bb < 16; ++bb) {
      float v = tile[(g * 16 + bb) * 33 + pp];
      u.b[bb] = v > 0.f ? 1 : (v < 0.f ? -1 : 0);
    }
    *(int4*)(A + (size_t)(P0 + pp) * 256 + g * 16) = u.v;
  }
}

// ---------------------------------------------------------------------------
// Final: BN apply + residual + PReLU. res aliases out (in-place safe).
// ---------------------------------------------------------------------------
__global__ __launch_bounds__(256) void bn_fin_apply(
    const short* __restrict__ dot, const float* __restrict__ res,
    const float* __restrict__ scale, const float* __restrict__ shift,
    const float* __restrict__ pa, float* __restrict__ out) {
  __shared__ short rawd[32 * 264];
  __shared__ float ssc[256], ssh[256];
  int t = threadIdx.x;
  int P0 = blockIdx.x * 32;
  ssc[t] = scale[t]; ssh[t] = shift[t];
  float ap = pa[0];
#pragma unroll
  for (int i = 0; i < 4; ++i) {
    int idx = i * 256 + t;
    int pl = idx >> 5, g = idx & 31;
    int4 d = *(const int4*)(dot + (size_t)(P0 + pl) * 256 + g * 8);
    *(int4*)(&rawd[pl * 264 + g * 8]) = d;
  }
  __syncthreads();
  int pl = t & 31, c0 = t >> 5;
  int P = P0 + pl;
  int b = P / HW, hw = P - b * HW;
  size_t base = (size_t)b * (NC * HW) + (size_t)c0 * HW + hw;
#pragma unroll
  for (int i = 0; i < 32; ++i) {
    int c = i * 8 + c0;
    size_t addr = base + (size_t)i * 8 * HW;
    float d = (float)rawd[pl * 264 + c];
    float v = fmaf(d, ssc[c], ssh[c]) + res[addr];
    out[addr] = v >= 0.0f ? v : ap * v;
  }
}

// ---------------------------------------------------------------------------
extern "C" void kernel_launch(void* const* d_in, const int* in_sizes, int n_in,
                              void* d_out, int out_size, void* d_ws, size_t ws_size,
                              hipStream_t stream) {
  const float* x   = (const float*)d_in[0];
  const float* w1  = (const float*)d_in[1];
  const float* w2  = (const float*)d_in[2];
  const float* g1  = (const float*)d_in[3];
  const float* b1  = (const float*)d_in[4];
  const float* g2  = (const float*)d_in[5];
  const float* b2  = (const float*)d_in[6];
  const float* pa1 = (const float*)d_in[7];
  const float* pa2 = (const float*)d_in[8];
  float* out = (float*)d_out;

  char* ws = (char*)d_ws;
  short*       dotb = (short*)ws;       ws += (size_t)NPIX * 256 * 2;  // 25.7MB (pre-guard for A)
  signed char* Abuf = (signed char*)ws; ws += (size_t)NPIX * 256;      // 12.85MB
  signed char* Wf1  = (signed char*)ws; ws += 589824;                  // post-guard for A
  signed char* Wf2  = (signed char*)ws; ws += 589824;
  float* alpha1 = (float*)ws; ws += 1024;
  float* alpha2 = (float*)ws; ws += 1024;
  unsigned long long* stats = (unsigned long long*)ws; ws += 1024 * 8;
  float* scale1 = (float*)ws; ws += 1024;
  float* shift1 = (float*)ws; ws += 1024;
  float* scale2 = (float*)ws; ws += 1024;
  float* shift2 = (float*)ws; ws += 1024;

  unsigned long long* sd1 = stats;
  unsigned long long* sq1 = stats + 256;
  unsigned long long* sd2 = stats + 512;
  unsigned long long* sq2 = stats + 768;

  init_stats<<<4, 256, 0, stream>>>(stats);
  alpha_k<<<512, 256, 0, stream>>>(w1, w2, alpha1, alpha2);
  wfrag_k<<<144, 256, 0, stream>>>(w1, w2, Wf1, Wf2);
  pack_x<<<NPIX / 32, 256, 0, stream>>>(x, Abuf);

  conv_mfma<<<784, 256, 0, stream>>>(Abuf, Wf1, dotb, sd1, sq1);
  bn_finalize<<<1, 256, 0, stream>>>(sd1, sq1, alpha1, g1, b1, scale1, shift1);
  bn_mid<<<NPIX / 32, 256, 0, stream>>>(dotb, x, scale1, shift1, pa1, out, Abuf);

  conv_mfma<<<784, 256, 0, stream>>>(Abuf, Wf2, dotb, sd2, sq2);
  bn_finalize<<<1, 256, 0, stream>>>(sd2, sq2, alpha2, g2, b2, scale2, shift2);
  bn_fin_apply<<<NPIX / 32, 256, 0, stream>>>(dotb, out, scale2, shift2, pa2, out);
}

// Round 4
// 175.491 us; speedup vs baseline: 3.2554x; 1.2038x over previous
//
#include <hip/hip_runtime.h>
#include <cstdint>

#define NB 64
#define NC 256
#define HW 784              // 28*28
#define NPIX (NB*HW)        // 50176
#define NELEM ((size_t)NB*NC*HW)

typedef int v4i  __attribute__((ext_vector_type(4)));
typedef int v16i __attribute__((ext_vector_type(16)));

union U16 { signed char b[16]; int4 v; };

// ---------------------------------------------------------------------------
// alpha = mean|w| per (conv, cout). One block per (conv,cout), coalesced.
// ---------------------------------------------------------------------------
__global__ __launch_bounds__(256) void alpha_k(
    const float* __restrict__ w1, const float* __restrict__ w2,
    float* __restrict__ al1, float* __restrict__ al2) {
  int blk = blockIdx.x;
  int conv = blk >> 8, cout = blk & 255;
  const float* w = (conv ? w2 : w1) + (size_t)cout * 2304;
  int t = threadIdx.x;
  float s = 0.0f;
  for (int i = t; i < 2304; i += 256) s += fabsf(w[i]);
  __shared__ float red[256];
  red[t] = s;
  __syncthreads();
  for (int st = 128; st > 0; st >>= 1) {
    if (t < st) red[t] += red[t + st];
    __syncthreads();
  }
  if (t == 0) (conv ? al2 : al1)[cout] = red[0] / 2304.0f;
}

// ---------------------------------------------------------------------------
// Pack weights into MFMA B-fragment order: Wf[tap][chunk(8)][cgroup(8)][lane(64)][16]
// value = sign(w[cout = cg*32+(lane&31)][cin = chunk*32+(lane>>5)*16+bb][tap])
// ---------------------------------------------------------------------------
__global__ __launch_bounds__(256) void wfrag_k(
    const float* __restrict__ w1, const float* __restrict__ w2,
    signed char* __restrict__ Wf1, signed char* __restrict__ Wf2) {
  int bi = blockIdx.x;            // 144 = 2 conv x 9 tap x 8 cgroup
  int conv = bi / 72, r = bi % 72, tap = r >> 3, cg = r & 7;
  const float* w = conv ? w2 : w1;
  signed char* Wf = conv ? Wf2 : Wf1;
  int t = threadIdx.x;
  for (int e = t; e < 512; e += 256) {
    int c = e >> 6, lane = e & 63;
    int cout = cg * 32 + (lane & 31);
    int cin0 = c * 32 + (lane >> 5) * 16;
    U16 u;
#pragma unroll
    for (int bb = 0; bb < 16; ++bb) {
      float v = w[((size_t)cout * 256 + cin0 + bb) * 9 + tap];
      u.b[bb] = v > 0.f ? 1 : (v < 0.f ? -1 : 0);
    }
    *(int4*)(Wf + ((((size_t)tap * 8 + c) * 8 + cg) * 64 + lane) * 16) = u.v;
  }
}

// ---------------------------------------------------------------------------
// x (NCHW f32) -> int8 signs, pixel-major [p][256]. LDS transpose, coalesced.
// ---------------------------------------------------------------------------
__global__ __launch_bounds__(256) void pack_x(
    const float* __restrict__ in, signed char* __restrict__ A) {
  __shared__ float tile[256 * 33];
  int t = threadIdx.x;
  int P0 = blockIdx.x * 32;
  int pl = t & 31, c0 = t >> 5;
  int P = P0 + pl;
  int b = P / HW, hw = P - b * HW;
  size_t base = (size_t)b * (NC * HW) + (size_t)c0 * HW + hw;
#pragma unroll
  for (int i = 0; i < 32; ++i)
    tile[(i * 8 + c0) * 33 + pl] = in[base + (size_t)i * 8 * HW];
  __syncthreads();
  int g = t >> 4, pls = t & 15;
#pragma unroll
  for (int ph = 0; ph < 2; ++ph) {
    int pp = ph * 16 + pls;
    U16 u;
#pragma unroll
    for (int bb = 0; bb < 16; ++bb) {
      float v = tile[(g * 16 + bb) * 33 + pp];
      u.b[bb] = v > 0.f ? 1 : (v < 0.f ? -1 : 0);
    }
    *(int4*)(A + (size_t)(P0 + pp) * 256 + g * 16) = u.v;
  }
}

// ---------------------------------------------------------------------------
// int8 MFMA conv 3x3 pad 1 + per-wave i32 BN-stat partials (no atomics).
// Block: 128 pixels x 128 couts; 4 waves of 64x64; halo staged once (48KB).
// Invalid taps read a zeroed LDS row (no per-value cndmask).
// ---------------------------------------------------------------------------
__global__ __launch_bounds__(256, 3) void conv_mfma(
    const signed char* __restrict__ A, const signed char* __restrict__ Wf,
    short* __restrict__ dotb,
    int* __restrict__ pd, int* __restrict__ pq) {
  __shared__ signed char As[192 * 256 + 256];
  int t = threadIdx.x;
  int lane = t & 63, wid = t >> 6;
  int mblk = blockIdx.x >> 1, nblk = blockIdx.x & 1;
  int p0 = mblk * 128;
  int wm = wid & 1, wn = wid >> 1;
  int khalf = lane >> 5;

  // stage halo rows p0-29 .. p0+162 with granule swizzle (key = pixel&15)
  {
    const signed char* src = A + (size_t)(p0 - 29) * 256;
#pragma unroll
    for (int i = 0; i < 12; ++i) {
      int off = i * 4096 + t * 16;
      int4 d = *(const int4*)(src + off);
      int r = off >> 8, g = (off >> 4) & 15;
      int gs = g ^ ((r + 3) & 15);      // (p0-29+r)&15 with p0%16==0
      *(int4*)(As + r * 256 + gs * 16) = d;
    }
    if (t < 16) { int4 z = {0, 0, 0, 0}; *(int4*)(As + 192 * 256 + t * 16) = z; }
  }

  // per-lane pixel geometry for the 2 M-fragments
  int prow[2], hh[2], ww[2];
#pragma unroll
  for (int i = 0; i < 2; ++i) {
    int p = p0 + wm * 64 + i * 32 + (lane & 31);
    prow[i] = p;
    int hw = p % HW;
    hh[i] = hw / 28;
    ww[i] = hw - hh[i] * 28;
  }
  __syncthreads();

  v16i acc00 = {0}, acc01 = {0}, acc10 = {0}, acc11 = {0};
  int cgbase = nblk * 4 + wn * 2;

  for (int ky = 0; ky < 3; ++ky) {
#pragma unroll
    for (int kx = 0; kx < 3; ++kx) {
      int tap = ky * 3 + kx;
      int dlt = (ky - 1) * 28 + (kx - 1);
      int rb[2], key[2];
#pragma unroll
      for (int i = 0; i < 2; ++i) {
        int hp = hh[i] + ky - 1, wp = ww[i] + kx - 1;
        bool val = ((unsigned)hp < 28u) && ((unsigned)wp < 28u);
        int pr = prow[i] + dlt;
        rb[i] = val ? (pr - (p0 - 29)) * 256 : 192 * 256;
        key[i] = val ? (pr & 15) : 0;
      }
      const signed char* wt = Wf + (size_t)tap * 65536;
#pragma unroll
      for (int c = 0; c < 8; ++c) {
        int gl = c * 2 + khalf;
        v4i a0 = *(const v4i*)(As + rb[0] + ((gl ^ key[0]) << 4));
        v4i a1 = *(const v4i*)(As + rb[1] + ((gl ^ key[1]) << 4));
        v4i w0 = *(const v4i*)(wt + (((size_t)c * 8 + cgbase) * 64 + lane) * 16);
        v4i w1 = *(const v4i*)(wt + (((size_t)c * 8 + cgbase + 1) * 64 + lane) * 16);
        acc00 = __builtin_amdgcn_mfma_i32_32x32x32_i8(a0, w0, acc00, 0, 0, 0);
        acc01 = __builtin_amdgcn_mfma_i32_32x32x32_i8(a0, w1, acc01, 0, 0, 0);
        acc10 = __builtin_amdgcn_mfma_i32_32x32x32_i8(a1, w0, acc10, 0, 0, 0);
        acc11 = __builtin_amdgcn_mfma_i32_32x32x32_i8(a1, w1, acc11, 0, 0, 0);
      }
    }
  }

  // stats: per-cout partial sums of dot and dot^2 over this wave's 64 rows
  int cb = nblk * 128 + wn * 64;
  int s0 = 0, sq0 = 0, s1 = 0, sq1 = 0;
#pragma unroll
  for (int q = 0; q < 16; ++q) {
    s0 += acc00[q] + acc10[q];
    sq0 += acc00[q] * acc00[q] + acc10[q] * acc10[q];
    s1 += acc01[q] + acc11[q];
    sq1 += acc01[q] * acc01[q] + acc11[q] * acc11[q];
  }
  s0 += __shfl_xor(s0, 32); sq0 += __shfl_xor(sq0, 32);
  s1 += __shfl_xor(s1, 32); sq1 += __shfl_xor(sq1, 32);
  if (lane < 32) {
    int row = mblk * 2 + wm;
    pd[row * 256 + cb + lane]      = s0;
    pq[row * 256 + cb + lane]      = sq0;
    pd[row * 256 + cb + 32 + lane] = s1;
    pq[row * 256 + cb + 32 + lane] = sq1;
  }

  // store dot int16, pixel-major [p][256]
#pragma unroll
  for (int i = 0; i < 2; ++i) {
    v16i aj0 = i ? acc10 : acc00;
    v16i aj1 = i ? acc11 : acc01;
    int pr = p0 + wm * 64 + i * 32 + 4 * khalf;
#pragma unroll
    for (int q = 0; q < 16; ++q) {
      int row = pr + (q & 3) + 8 * (q >> 2);
      size_t base = (size_t)row * 256 + cb + (lane & 31);
      dotb[base]      = (short)aj0[q];
      dotb[base + 32] = (short)aj1[q];
    }
  }
}

// ---------------------------------------------------------------------------
// Finalize BN from i32 partials. One block per channel.
// y = dot*0.1*alpha; scale[c] applies to raw dot; shift[c] absolute.
// ---------------------------------------------------------------------------
__global__ __launch_bounds__(256) void bn_finalize(
    const int* __restrict__ pd, const int* __restrict__ pq,
    const float* __restrict__ alpha, const float* __restrict__ gamma,
    const float* __restrict__ beta, float* __restrict__ scale,
    float* __restrict__ shift) {
  int c = blockIdx.x, t = threadIdx.x;
  long long D = 0, D2 = 0;
  for (int r = t; r < 784; r += 256) {
    D  += (long long)pd[r * 256 + c];
    D2 += (long long)pq[r * 256 + c];
  }
  __shared__ long long rd[256], rq[256];
  rd[t] = D; rq[t] = D2;
  __syncthreads();
  for (int st = 128; st > 0; st >>= 1) {
    if (t < st) { rd[t] += rd[t + st]; rq[t] += rq[t + st]; }
    __syncthreads();
  }
  if (t == 0) {
    float sc = 0.1f * alpha[c];
    const float invN = 1.0f / (float)(NB * HW);
    float md  = (float)rd[0] * invN;
    float ex2 = (float)rq[0] * invN;
    float var = sc * sc * (ex2 - md * md);
    float rs = rsqrtf(var + 1e-5f);
    float g = gamma[c];
    scale[c] = rs * g * sc;
    shift[c] = beta[c] - sc * md * rs * g;
  }
}

// ---------------------------------------------------------------------------
// BN apply + residual + PReLU + int8 sign-pack.  dot int16 pixel-major in,
// x NCHW in, a1 NCHW out, A int8 out.
// ---------------------------------------------------------------------------
__global__ __launch_bounds__(256) void bn_mid(
    const short* __restrict__ dot, const float* __restrict__ x,
    const float* __restrict__ scale, const float* __restrict__ shift,
    const float* __restrict__ pa, float* __restrict__ a1,
    signed char* __restrict__ A) {
  __shared__ short rawd[32 * 264];
  __shared__ float tile[256 * 33];
  __shared__ float ssc[256], ssh[256];
  int t = threadIdx.x;
  int P0 = blockIdx.x * 32;
  ssc[t] = scale[t]; ssh[t] = shift[t];
  float ap = pa[0];
#pragma unroll
  for (int i = 0; i < 4; ++i) {
    int idx = i * 256 + t;
    int pl = idx >> 5, g = idx & 31;
    int4 d = *(const int4*)(dot + (size_t)(P0 + pl) * 256 + g * 8);
    *(int4*)(&rawd[pl * 264 + g * 8]) = d;
  }
  __syncthreads();
  int pl = t & 31, c0 = t >> 5;
  int P = P0 + pl;
  int b = P / HW, hw = P - b * HW;
  size_t base = (size_t)b * (NC * HW) + (size_t)c0 * HW + hw;
#pragma unroll
  for (int i = 0; i < 32; ++i) {
    int c = i * 8 + c0;
    size_t addr = base + (size_t)i * 8 * HW;
    float d = (float)rawd[pl * 264 + c];
    float v = fmaf(d, ssc[c], ssh[c]) + x[addr];
    float o = v >= 0.0f ? v : ap * v;
    a1[addr] = o;
    tile[c * 33 + pl] = o;
  }
  __syncthreads();
  int g = t >> 4, pls = t & 15;
#pragma unroll
  for (int ph = 0; ph < 2; ++ph) {
    int pp = ph * 16 + pls;
    U16 u;
#pragma unroll
    for (int bb = 0; bb < 16; ++bb) {
      float v = tile[(g * 16 + bb) * 33 + pp];
      u.b[bb] = v > 0.f ? 1 : (v < 0.f ? -1 : 0);
    }
    *(int4*)(A + (size_t)(P0 + pp) * 256 + g * 16) = u.v;
  }
}

// ---------------------------------------------------------------------------
// Final: BN apply + residual + PReLU. res aliases out (in-place safe).
// ---------------------------------------------------------------------------
__global__ __launch_bounds__(256) void bn_fin_apply(
    const short* __restrict__ dot, const float* __restrict__ res,
    const float* __restrict__ scale, const float* __restrict__ shift,
    const float* __restrict__ pa, float* __restrict__ out) {
  __shared__ short rawd[32 * 264];
  __shared__ float ssc[256], ssh[256];
  int t = threadIdx.x;
  int P0 = blockIdx.x * 32;
  ssc[t] = scale[t]; ssh[t] = shift[t];
  float ap = pa[0];
#pragma unroll
  for (int i = 0; i < 4; ++i) {
    int idx = i * 256 + t;
    int pl = idx >> 5, g = idx & 31;
    int4 d = *(const int4*)(dot + (size_t)(P0 + pl) * 256 + g * 8);
    *(int4*)(&rawd[pl * 264 + g * 8]) = d;
  }
  __syncthreads();
  int pl = t & 31, c0 = t >> 5;
  int P = P0 + pl;
  int b = P / HW, hw = P - b * HW;
  size_t base = (size_t)b * (NC * HW) + (size_t)c0 * HW + hw;
#pragma unroll
  for (int i = 0; i < 32; ++i) {
    int c = i * 8 + c0;
    size_t addr = base + (size_t)i * 8 * HW;
    float d = (float)rawd[pl * 264 + c];
    float v = fmaf(d, ssc[c], ssh[c]) + res[addr];
    out[addr] = v >= 0.0f ? v : ap * v;
  }
}

// ---------------------------------------------------------------------------
extern "C" void kernel_launch(void* const* d_in, const int* in_sizes, int n_in,
                              void* d_out, int out_size, void* d_ws, size_t ws_size,
                              hipStream_t stream) {
  const float* x   = (const float*)d_in[0];
  const float* w1  = (const float*)d_in[1];
  const float* w2  = (const float*)d_in[2];
  const float* g1  = (const float*)d_in[3];
  const float* b1  = (const float*)d_in[4];
  const float* g2  = (const float*)d_in[5];
  const float* b2  = (const float*)d_in[6];
  const float* pa1 = (const float*)d_in[7];
  const float* pa2 = (const float*)d_in[8];
  float* out = (float*)d_out;

  char* ws = (char*)d_ws;
  short*       dotb = (short*)ws;       ws += (size_t)NPIX * 256 * 2;  // 25.7MB (pre-guard for A)
  signed char* Abuf = (signed char*)ws; ws += (size_t)NPIX * 256;      // 12.85MB
  signed char* Wf1  = (signed char*)ws; ws += 589824;                  // post-guard for A
  signed char* Wf2  = (signed char*)ws; ws += 589824;
  int* pd1 = (int*)ws; ws += 784 * 256 * 4;                            // 0.8MB
  int* pq1 = (int*)ws; ws += 784 * 256 * 4;
  int* pd2 = (int*)ws; ws += 784 * 256 * 4;
  int* pq2 = (int*)ws; ws += 784 * 256 * 4;
  float* alpha1 = (float*)ws; ws += 1024;
  float* alpha2 = (float*)ws; ws += 1024;
  float* scale1 = (float*)ws; ws += 1024;
  float* shift1 = (float*)ws; ws += 1024;
  float* scale2 = (float*)ws; ws += 1024;
  float* shift2 = (float*)ws; ws += 1024;

  alpha_k<<<512, 256, 0, stream>>>(w1, w2, alpha1, alpha2);
  wfrag_k<<<144, 256, 0, stream>>>(w1, w2, Wf1, Wf2);
  pack_x<<<NPIX / 32, 256, 0, stream>>>(x, Abuf);

  conv_mfma<<<784, 256, 0, stream>>>(Abuf, Wf1, dotb, pd1, pq1);
  bn_finalize<<<256, 256, 0, stream>>>(pd1, pq1, alpha1, g1, b1, scale1, shift1);
  bn_mid<<<NPIX / 32, 256, 0, stream>>>(dotb, x, scale1, shift1, pa1, out, Abuf);

  conv_mfma<<<784, 256, 0, stream>>>(Abuf, Wf2, dotb, pd2, pq2);
  bn_finalize<<<256, 256, 0, stream>>>(pd2, pq2, alpha2, g2, b2, scale2, shift2);
  bn_fin_apply<<<NPIX / 32, 256, 0, stream>>>(dotb, out, scale2, shift2, pa2, out);
}